// Round 5
// baseline (436.104 us; speedup 1.0000x reference)
//
#include <hip/hip_runtime.h>
#include <math.h>

// Problem constants (fixed by setup_inputs)
constexpr int N_ = 8, C_ = 256, F_ = 16, WH_ = 784;
constexpr int NF = N_ * F_;          // 128
constexpr int CH_STRIDE = F_ * WH_;  // 12544 floats between channels
constexpr int SPLITS = 8;            // channel splits in phase 1
constexpr int CPS = C_ / SPLITS;     // 32 channels per split
constexpr int COUT_SZ = NF * WH_;    // 100352 floats (c output)
constexpr int P4 = WH_ / 4;          // 196 float4 per spatial row
constexpr unsigned GRID = 1024;      // 4 blocks/CU x 256 CUs -> co-resident

__device__ inline float wave_reduce_sum(float v) {
#pragma unroll
  for (int o = 32; o > 0; o >>= 1) v += __shfl_down(v, o, 64);
  return v;
}
__device__ inline float wave_reduce_max(float v) {
#pragma unroll
  for (int o = 32; o > 0; o >>= 1) v = fmaxf(v, __shfl_down(v, o, 64));
  return v;
}

// Manual grid barrier (graph-capturable, unlike hipLaunchCooperativeKernel).
// Bounded spin: if co-residency is ever violated we produce a wrong answer
// (diagnosable) instead of a hang.
__device__ inline void grid_barrier(unsigned* bar, unsigned target) {
  __syncthreads();
  if (threadIdx.x == 0) {
    __threadfence();  // release: flush our writes device-wide
    __hip_atomic_fetch_add(bar, 1u, __ATOMIC_ACQ_REL, __HIP_MEMORY_SCOPE_AGENT);
    unsigned spins = 0;
    while (__hip_atomic_load(bar, __ATOMIC_ACQUIRE, __HIP_MEMORY_SCOPE_AGENT) < target) {
      __builtin_amdgcn_s_sleep(2);
      if (++spins > (1u << 26)) break;  // safety valve
    }
    __threadfence();  // acquire: invalidate stale cache lines
  }
  __syncthreads();
}

__global__ __launch_bounds__(64) void k_init(unsigned* bar) {
  if (threadIdx.x < 2) bar[threadIdx.x] = 0u;
}

// Fused persistent kernel: phase1 partial dots -> phase2 softmax -> phase3 pool.
__global__ __launch_bounds__(256, 4) void mfla_fused(
    const float* __restrict__ l, const float* __restrict__ g,
    const float* __restrict__ w, float* __restrict__ out,
    float* __restrict__ part, float* __restrict__ a, unsigned* bar) {
  __shared__ float red[4];
  __shared__ float bc;
  const int b = blockIdx.x;
  const int t = threadIdx.x;
  const int lane = t & 63, wv = t >> 6;

  // ---- Phase 1: partial channel-dot. b -> (nf = b>>3, split s = b&7)
  {
    const int nf = b >> 3, s = b & 7;
    const int n = nf >> 4, f = nf & 15;
    if (t < P4) {
      const float* base = l + ((size_t)(n * C_ + s * CPS) * F_ + f) * WH_ + 4 * t;
      const float* wp = w + s * CPS;
      float4 acc = make_float4(0.f, 0.f, 0.f, 0.f);
#pragma unroll 8
      for (int j = 0; j < CPS; ++j) {
        const float wj = wp[j];  // wave-uniform -> scalar load
        const float4 v = *reinterpret_cast<const float4*>(base + (size_t)j * CH_STRIDE);
        acc.x = fmaf(v.x, wj, acc.x);
        acc.y = fmaf(v.y, wj, acc.y);
        acc.z = fmaf(v.z, wj, acc.z);
        acc.w = fmaf(v.w, wj, acc.w);
      }
      *reinterpret_cast<float4*>(part + (size_t)b * WH_ + 4 * t) = acc;
    }
  }

  grid_barrier(bar + 0, GRID);

  // ---- Phase 2: reduce partials + gb -> c (d_out), softmax -> a. 128 blocks.
  if (b < NF) {
    const int nf = b;
    const int n = nf >> 4;

    float gv = g[n * C_ + t] * w[t];
    gv = wave_reduce_sum(gv);
    if (lane == 0) red[wv] = gv;
    __syncthreads();
    if (t == 0) bc = red[0] + red[1] + red[2] + red[3];
    __syncthreads();
    const float gb = bc;

    float4 cv = make_float4(-3.4e38f, -3.4e38f, -3.4e38f, -3.4e38f);
    if (t < P4) {
      const float* pp = part + (size_t)nf * SPLITS * WH_ + 4 * t;
      float4 s0 = make_float4(0.f, 0.f, 0.f, 0.f);
#pragma unroll
      for (int s = 0; s < SPLITS; ++s) {
        const float4 v = *reinterpret_cast<const float4*>(pp + (size_t)s * WH_);
        s0.x += v.x; s0.y += v.y; s0.z += v.z; s0.w += v.w;
      }
      cv = make_float4(s0.x + gb, s0.y + gb, s0.z + gb, s0.w + gb);
      *reinterpret_cast<float4*>(out + (size_t)nf * WH_ + 4 * t) = cv;
    }

    float m = fmaxf(fmaxf(cv.x, cv.y), fmaxf(cv.z, cv.w));
    m = wave_reduce_max(m);
    __syncthreads();
    if (lane == 0) red[wv] = m;
    __syncthreads();
    if (t == 0) bc = fmaxf(fmaxf(red[0], red[1]), fmaxf(red[2], red[3]));
    __syncthreads();
    const float cmax = bc;

    float4 e = make_float4(0.f, 0.f, 0.f, 0.f);
    if (t < P4) {
      e.x = expf(cv.x - cmax);
      e.y = expf(cv.y - cmax);
      e.z = expf(cv.z - cmax);
      e.w = expf(cv.w - cmax);
    }
    float ssum = (e.x + e.y) + (e.z + e.w);
    ssum = wave_reduce_sum(ssum);
    __syncthreads();
    if (lane == 0) red[wv] = ssum;
    __syncthreads();
    if (t == 0) bc = 1.f / (red[0] + red[1] + red[2] + red[3]);
    __syncthreads();
    const float inv = bc;

    if (t < P4) {
      e.x *= inv; e.y *= inv; e.z *= inv; e.w *= inv;
      *reinterpret_cast<float4*>(a + (size_t)nf * WH_ + 4 * t) = e;
    }
  }

  grid_barrier(bar + 1, GRID);

  // ---- Phase 3: pooling. b -> (n = b>>7, f = (b>>3)&15, cg = b&7).
  // Each wave register-caches its a[n,f,:] slice once; 8 channels per wave.
  {
    const int n = b >> 7;
    const int f = (b >> 3) & 15;
    const int cg = b & 7;
    const int p0 = lane << 2;

    const float* ar = a + ((size_t)n * F_ + f) * WH_;
    const float4 a0 = *reinterpret_cast<const float4*>(ar + p0);
    const float4 a1 = *reinterpret_cast<const float4*>(ar + p0 + 256);
    const float4 a2 = *reinterpret_cast<const float4*>(ar + p0 + 512);
    float4 a3 = make_float4(0.f, 0.f, 0.f, 0.f);
    if (lane < 4) a3 = *reinterpret_cast<const float4*>(ar + 768 + p0);

    const int c0 = cg * 32 + wv * 8;  // this wave's first channel
#pragma unroll 2
    for (int k = 0; k < 8; ++k) {
      const int c = c0 + k;
      const float* lr = l + ((size_t)(n * C_ + c) * F_ + f) * WH_;
      const float4 x0 = *reinterpret_cast<const float4*>(lr + p0);
      const float4 x1 = *reinterpret_cast<const float4*>(lr + p0 + 256);
      const float4 x2 = *reinterpret_cast<const float4*>(lr + p0 + 512);
      float acc = 0.f;
      acc = fmaf(x0.x, a0.x, acc); acc = fmaf(x0.y, a0.y, acc);
      acc = fmaf(x0.z, a0.z, acc); acc = fmaf(x0.w, a0.w, acc);
      acc = fmaf(x1.x, a1.x, acc); acc = fmaf(x1.y, a1.y, acc);
      acc = fmaf(x1.z, a1.z, acc); acc = fmaf(x1.w, a1.w, acc);
      acc = fmaf(x2.x, a2.x, acc); acc = fmaf(x2.y, a2.y, acc);
      acc = fmaf(x2.z, a2.z, acc); acc = fmaf(x2.w, a2.w, acc);
      if (lane < 4) {
        const float4 x3 = *reinterpret_cast<const float4*>(lr + 768 + p0);
        acc = fmaf(x3.x, a3.x, acc); acc = fmaf(x3.y, a3.y, acc);
        acc = fmaf(x3.z, a3.z, acc); acc = fmaf(x3.w, a3.w, acc);
      }
      acc = wave_reduce_sum(acc);
      if (lane == 0) out[COUT_SZ + (size_t)(n * C_ + c) * F_ + f] = acc;
    }
  }
}

extern "C" void kernel_launch(void* const* d_in, const int* in_sizes, int n_in,
                              void* d_out, int out_size, void* d_ws, size_t ws_size,
                              hipStream_t stream) {
  const float* l = (const float*)d_in[0];
  const float* g = (const float*)d_in[1];
  const float* w = (const float*)d_in[2];
  float* out = (float*)d_out;
  float* part = (float*)d_ws;                       // 1024*784 floats = 3.2 MB
  float* a = part + (size_t)SPLITS * NF * WH_;      // 128*784 floats = 0.4 MB
  unsigned* bar = (unsigned*)(a + (size_t)NF * WH_);

  k_init<<<dim3(1), dim3(64), 0, stream>>>(bar);
  mfla_fused<<<dim3(GRID), dim3(256), 0, stream>>>(l, g, w, out, part, a, bar);
}

// Round 6
// 340.287 us; speedup vs baseline: 1.2816x; 1.2816x over previous
//
#include <hip/hip_runtime.h>
#include <math.h>

// Problem constants (fixed by setup_inputs)
constexpr int N_ = 8, C_ = 256, F_ = 16, WH_ = 784;
constexpr int NF = N_ * F_;          // 128
constexpr int CH_STRIDE = F_ * WH_;  // 12544 floats between channels
constexpr int SPLITS = 8;            // channel splits in phase 1
constexpr int CPS = C_ / SPLITS;     // 32 channels per split
constexpr int COUT_SZ = NF * WH_;    // 100352 floats (c output)
constexpr int P4 = WH_ / 4;          // 196 float4 per spatial row
constexpr unsigned GRID = 1024;      // 4 blocks/CU x 256 CUs -> co-resident

// Hierarchical barrier layout (per barrier): 32 leaf lines + root line + flag line.
constexpr int NLEAF = 32;
constexpr unsigned LEAF_TARGET = GRID / NLEAF;  // 32 arrivals per leaf
constexpr int BAR_WORDS = (NLEAF + 2) * 16;     // 16 uints (64 B) per line

__device__ inline float wave_reduce_sum(float v) {
#pragma unroll
  for (int o = 32; o > 0; o >>= 1) v += __shfl_down(v, o, 64);
  return v;
}
__device__ inline float wave_reduce_max(float v) {
#pragma unroll
  for (int o = 32; o > 0; o >>= 1) v = fmaxf(v, __shfl_down(v, o, 64));
  return v;
}

// Contention-safe grid barrier: hierarchical arrival (32-way leaf fan-in on
// separate cache lines -> root), single release-flag line polled read-only
// with heavy s_sleep backoff. Release/acquire chain through ACQ_REL RMWs
// gives cross-XCD visibility. Bounded spin: co-residency failure -> wrong
// answer (diagnosable), not a hang.
__device__ inline void grid_barrier(unsigned* base) {
  __syncthreads();
  if (threadIdx.x == 0) {
    unsigned* leaf = base + (blockIdx.x & (NLEAF - 1)) * 16;
    unsigned* root = base + NLEAF * 16;
    unsigned* flag = base + (NLEAF + 1) * 16;
    const unsigned old =
        __hip_atomic_fetch_add(leaf, 1u, __ATOMIC_ACQ_REL, __HIP_MEMORY_SCOPE_AGENT);
    if (old == LEAF_TARGET - 1) {
      const unsigned r =
          __hip_atomic_fetch_add(root, 1u, __ATOMIC_ACQ_REL, __HIP_MEMORY_SCOPE_AGENT);
      if (r == NLEAF - 1)
        __hip_atomic_store(flag, 1u, __ATOMIC_RELEASE, __HIP_MEMORY_SCOPE_AGENT);
    }
    unsigned spins = 0;
    while (__hip_atomic_load(flag, __ATOMIC_ACQUIRE, __HIP_MEMORY_SCOPE_AGENT) == 0u) {
      __builtin_amdgcn_s_sleep(32);            // ~2048 cycles between polls
      if (++spins > (1u << 20)) break;         // safety valve (~1 s worst case)
    }
  }
  __syncthreads();
}

__global__ __launch_bounds__(256) void k_init(unsigned* bar) {
  for (int i = threadIdx.x; i < 2 * BAR_WORDS; i += 256) bar[i] = 0u;
}

// Fused persistent kernel: phase1 partial dots -> phase2 softmax -> phase3 pool.
__global__ __launch_bounds__(256, 4) void mfla_fused(
    const float* __restrict__ l, const float* __restrict__ g,
    const float* __restrict__ w, float* __restrict__ out,
    float* __restrict__ part, float* __restrict__ a, unsigned* bar) {
  __shared__ float red[4];
  __shared__ float bc;
  const int b = blockIdx.x;
  const int t = threadIdx.x;
  const int lane = t & 63, wv = t >> 6;

  // ---- Phase 1: partial channel-dot. b -> (nf = b>>3, split s = b&7)
  {
    const int nf = b >> 3, s = b & 7;
    const int n = nf >> 4, f = nf & 15;
    if (t < P4) {
      const float* base = l + ((size_t)(n * C_ + s * CPS) * F_ + f) * WH_ + 4 * t;
      const float* wp = w + s * CPS;
      float4 acc = make_float4(0.f, 0.f, 0.f, 0.f);
#pragma unroll 8
      for (int j = 0; j < CPS; ++j) {
        const float wj = wp[j];  // wave-uniform -> scalar load
        const float4 v = *reinterpret_cast<const float4*>(base + (size_t)j * CH_STRIDE);
        acc.x = fmaf(v.x, wj, acc.x);
        acc.y = fmaf(v.y, wj, acc.y);
        acc.z = fmaf(v.z, wj, acc.z);
        acc.w = fmaf(v.w, wj, acc.w);
      }
      *reinterpret_cast<float4*>(part + (size_t)b * WH_ + 4 * t) = acc;
    }
  }

  grid_barrier(bar);

  // ---- Phase 2: reduce partials + gb -> c (d_out), softmax -> a. 128 blocks.
  if (b < NF) {
    const int nf = b;
    const int n = nf >> 4;

    float gv = g[n * C_ + t] * w[t];
    gv = wave_reduce_sum(gv);
    if (lane == 0) red[wv] = gv;
    __syncthreads();
    if (t == 0) bc = red[0] + red[1] + red[2] + red[3];
    __syncthreads();
    const float gb = bc;

    float4 cv = make_float4(-3.4e38f, -3.4e38f, -3.4e38f, -3.4e38f);
    if (t < P4) {
      const float* pp = part + (size_t)nf * SPLITS * WH_ + 4 * t;
      float4 s0 = make_float4(0.f, 0.f, 0.f, 0.f);
#pragma unroll
      for (int s = 0; s < SPLITS; ++s) {
        const float4 v = *reinterpret_cast<const float4*>(pp + (size_t)s * WH_);
        s0.x += v.x; s0.y += v.y; s0.z += v.z; s0.w += v.w;
      }
      cv = make_float4(s0.x + gb, s0.y + gb, s0.z + gb, s0.w + gb);
      *reinterpret_cast<float4*>(out + (size_t)nf * WH_ + 4 * t) = cv;
    }

    float m = fmaxf(fmaxf(cv.x, cv.y), fmaxf(cv.z, cv.w));
    m = wave_reduce_max(m);
    __syncthreads();
    if (lane == 0) red[wv] = m;
    __syncthreads();
    if (t == 0) bc = fmaxf(fmaxf(red[0], red[1]), fmaxf(red[2], red[3]));
    __syncthreads();
    const float cmax = bc;

    float4 e = make_float4(0.f, 0.f, 0.f, 0.f);
    if (t < P4) {
      e.x = expf(cv.x - cmax);
      e.y = expf(cv.y - cmax);
      e.z = expf(cv.z - cmax);
      e.w = expf(cv.w - cmax);
    }
    float ssum = (e.x + e.y) + (e.z + e.w);
    ssum = wave_reduce_sum(ssum);
    __syncthreads();
    if (lane == 0) red[wv] = ssum;
    __syncthreads();
    if (t == 0) bc = 1.f / (red[0] + red[1] + red[2] + red[3]);
    __syncthreads();
    const float inv = bc;

    if (t < P4) {
      e.x *= inv; e.y *= inv; e.z *= inv; e.w *= inv;
      *reinterpret_cast<float4*>(a + (size_t)nf * WH_ + 4 * t) = e;
    }
  }

  grid_barrier(bar + BAR_WORDS);

  // ---- Phase 3: pooling. b -> (n = b>>7, f = (b>>3)&15, cg = b&7).
  // Each wave register-caches its a[n,f,:] slice once; 8 channels per wave.
  {
    const int n = b >> 7;
    const int f = (b >> 3) & 15;
    const int cg = b & 7;
    const int p0 = lane << 2;

    const float* ar = a + ((size_t)n * F_ + f) * WH_;
    const float4 a0 = *reinterpret_cast<const float4*>(ar + p0);
    const float4 a1 = *reinterpret_cast<const float4*>(ar + p0 + 256);
    const float4 a2 = *reinterpret_cast<const float4*>(ar + p0 + 512);
    float4 a3 = make_float4(0.f, 0.f, 0.f, 0.f);
    if (lane < 4) a3 = *reinterpret_cast<const float4*>(ar + 768 + p0);

    const int c0 = cg * 32 + wv * 8;  // this wave's first channel
#pragma unroll 2
    for (int k = 0; k < 8; ++k) {
      const int c = c0 + k;
      const float* lr = l + ((size_t)(n * C_ + c) * F_ + f) * WH_;
      const float4 x0 = *reinterpret_cast<const float4*>(lr + p0);
      const float4 x1 = *reinterpret_cast<const float4*>(lr + p0 + 256);
      const float4 x2 = *reinterpret_cast<const float4*>(lr + p0 + 512);
      float acc = 0.f;
      acc = fmaf(x0.x, a0.x, acc); acc = fmaf(x0.y, a0.y, acc);
      acc = fmaf(x0.z, a0.z, acc); acc = fmaf(x0.w, a0.w, acc);
      acc = fmaf(x1.x, a1.x, acc); acc = fmaf(x1.y, a1.y, acc);
      acc = fmaf(x1.z, a1.z, acc); acc = fmaf(x1.w, a1.w, acc);
      acc = fmaf(x2.x, a2.x, acc); acc = fmaf(x2.y, a2.y, acc);
      acc = fmaf(x2.z, a2.z, acc); acc = fmaf(x2.w, a2.w, acc);
      if (lane < 4) {
        const float4 x3 = *reinterpret_cast<const float4*>(lr + 768 + p0);
        acc = fmaf(x3.x, a3.x, acc); acc = fmaf(x3.y, a3.y, acc);
        acc = fmaf(x3.z, a3.z, acc); acc = fmaf(x3.w, a3.w, acc);
      }
      acc = wave_reduce_sum(acc);
      if (lane == 0) out[COUT_SZ + (size_t)(n * C_ + c) * F_ + f] = acc;
    }
  }
}

extern "C" void kernel_launch(void* const* d_in, const int* in_sizes, int n_in,
                              void* d_out, int out_size, void* d_ws, size_t ws_size,
                              hipStream_t stream) {
  const float* l = (const float*)d_in[0];
  const float* g = (const float*)d_in[1];
  const float* w = (const float*)d_in[2];
  float* out = (float*)d_out;
  float* part = (float*)d_ws;                       // 1024*784 floats = 3.2 MB
  float* a = part + (size_t)SPLITS * NF * WH_;      // 128*784 floats = 0.4 MB
  unsigned* bar = (unsigned*)(a + (size_t)NF * WH_);

  k_init<<<dim3(1), dim3(256), 0, stream>>>(bar);
  mfla_fused<<<dim3(GRID), dim3(256), 0, stream>>>(l, g, w, out, part, a, bar);
}